// Round 1
// baseline (9.482 us; speedup 1.0000x reference)
//
#include <hip/hip_runtime.h>

// QuantumMLPHead: RY(x+shift) on 14 qubits -> ring of CNOTs -> <Z_0>.
// Closed form: the CNOT ring maps bit0 -> a_1 ^ ... ^ a_13 (basis permutation),
// and the pre-CNOT state is a product state, so
//   <Z_0> = prod_{i=1..13} cos(x[b,i] + shift[i]).
// Qubit 0 does not appear in the result.
//
// This version:
//  - LDS-stages each block's 256x14 input panel with fully-coalesced dword
//    loads (each global load instruction covers 1024 contiguous bytes),
//    padded to row stride 15 (odd stride -> max 2 lanes/bank on the scalar
//    per-row reads = conflict-free per m136).
//  - Uses __cosf (v_cos_f32, input pre-scaled to revolutions) instead of
//    libm cosf: args are |x| <~ 5, well inside the HW range; ~14x fewer
//    VALU ops than __ocml_cos_f32's branchy range reduction.

#define QM_BATCH 4096
#define QM_NQ    14
#define QM_BLOCK 256
#define QM_PAD   15   // LDS row stride (odd => bank-conflict-free scalar reads)

__global__ __launch_bounds__(QM_BLOCK) void QuantumMLPHead_65481071410640_kernel(
    const float* __restrict__ x,      // [BATCH, NQ]
    const float* __restrict__ shift,  // [NQ]
    float* __restrict__ out)          // [BATCH]
{
    __shared__ float tile[QM_BLOCK * QM_PAD];  // 15 KB

    const int tid  = threadIdx.x;
    const int base = blockIdx.x * (QM_BLOCK * QM_NQ);

    // Coalesced staging: 14 iterations, each a 256-lane contiguous dword load.
#pragma unroll
    for (int j = 0; j < QM_NQ; ++j) {
        const int k = j * QM_BLOCK + tid;     // 0 .. 3583
        const int r = k / QM_NQ;              // magic-mul, cheap
        const int c = k - r * QM_NQ;
        tile[r * QM_PAD + c] = x[base + k];
    }
    __syncthreads();

    const float* row = tile + tid * QM_PAD;
    float prod = 1.0f;
#pragma unroll
    for (int i = 1; i < QM_NQ; ++i) {
        prod *= __cosf(row[i] + shift[i]);    // v_cos_f32, args << range limit
    }
    out[blockIdx.x * QM_BLOCK + tid] = prod;
}

extern "C" void kernel_launch(void* const* d_in, const int* in_sizes, int n_in,
                              void* d_out, int out_size, void* d_ws, size_t ws_size,
                              hipStream_t stream) {
    const float* x     = (const float*)d_in[0];  // [4096, 14] f32
    const float* shift = (const float*)d_in[1];  // [14] f32
    float* out = (float*)d_out;                  // [4096] f32

    dim3 block(QM_BLOCK);
    dim3 grid(QM_BATCH / QM_BLOCK);              // 4096 % 256 == 0, no tail guard
    QuantumMLPHead_65481071410640_kernel<<<grid, block, 0, stream>>>(x, shift, out);
}